// Round 12
// baseline (793.903 us; speedup 1.0000x reference)
//
#include <hip/hip_runtime.h>

#define SCALE 10.0f           // 1 / TEMPERATURE
#define EPS_MARGIN 0.011f     // bf16-dot err (0.008) + u16 round-up/trunc slack
#define PAIR_CAP 32768

typedef __attribute__((ext_vector_type(8))) short short8;
typedef __attribute__((ext_vector_type(4))) float floatx4;

#define MFMA16(a, b, c) __builtin_amdgcn_mfma_f32_16x16x32_bf16((a), (b), (c), 0, 0, 0)

// ---------- helpers ----------
__device__ __forceinline__ unsigned int ordered_bits(float f) {
    unsigned int b = __float_as_uint(f);
    return (b & 0x80000000u) ? ~b : (b | 0x80000000u);
}
__device__ __forceinline__ float from_ordered(unsigned int u) {
    return __uint_as_float((u & 0x80000000u) ? (u ^ 0x80000000u) : ~u);
}
__device__ __forceinline__ short bf_rne(float x) {   // fp32 -> bf16 bits, RNE
    unsigned int u = __float_as_uint(x);
    return (short)((u + 0x7FFFu + ((u >> 16) & 1u)) >> 16);
}

// ---------- K1: l2-normalize p1,p2 -> pn fp32 + pnb bf16; init state --------
__global__ void k_prep(const float* __restrict__ p1, const float* __restrict__ p2,
                       float* __restrict__ pn, short* __restrict__ pnb,
                       unsigned long long* __restrict__ best,
                       unsigned int* __restrict__ paircnt, float* __restrict__ sums) {
    int row = blockIdx.x;               // 0..4095
    int t = threadIdx.x;                // 0..63
    const float* src = (row < 2048) ? (p1 + (size_t)row * 128)
                                    : (p2 + (size_t)(row - 2048) * 128);
    float2 v = ((const float2*)src)[t];
    float ss = v.x * v.x + v.y * v.y;
    #pragma unroll
    for (int o = 32; o; o >>= 1) ss += __shfl_xor(ss, o);
    float inv = 1.0f / sqrtf(ss);
    float2 o2; o2.x = v.x * inv; o2.y = v.y * inv;
    ((float2*)(pn + (size_t)row * 128))[t] = o2;
    unsigned int pk = (unsigned int)(unsigned short)bf_rne(o2.x)
                    | ((unsigned int)(unsigned short)bf_rne(o2.y) << 16);
    ((unsigned int*)(pnb + (size_t)row * 128))[t] = pk;
    if (t == 0) { best[row] = 0ULL; if (row == 0) *paircnt = 0u; }
    if (row < 128) sums[row * 64 + t] = 0.0f;
}

// ---------- K2: queue fp32 -> qb bf16 ----------
__global__ void k_qcvt(const float* __restrict__ queue, short* __restrict__ qb) {
    size_t i = ((size_t)blockIdx.x * 256 + threadIdx.x) * 8;
    float4 f0 = *(const float4*)(queue + i);
    float4 f1 = *(const float4*)(queue + i + 4);
    short8 o;
    o[0] = bf_rne(f0.x); o[1] = bf_rne(f0.y); o[2] = bf_rne(f0.z); o[3] = bf_rne(f0.w);
    o[4] = bf_rne(f1.x); o[5] = bf_rne(f1.y); o[6] = bf_rne(f1.z); o[7] = bf_rne(f1.w);
    *(short8*)(qb + i) = o;
}

// ---------- 16-q tile, k-outer / rf-inner (8-way ILP), fmax into rmax --------
__device__ __forceinline__ void tile_max(const short8 A[8][4],
                                         short8 b0, short8 b1, short8 b2, short8 b3,
                                         float rmax[8][4]) {
    floatx4 acc[8];
    floatx4 zero = {0.0f, 0.0f, 0.0f, 0.0f};
    #pragma unroll
    for (int rf = 0; rf < 8; ++rf) acc[rf] = MFMA16(A[rf][0], b0, zero);
    #pragma unroll
    for (int rf = 0; rf < 8; ++rf) acc[rf] = MFMA16(A[rf][1], b1, acc[rf]);
    #pragma unroll
    for (int rf = 0; rf < 8; ++rf) acc[rf] = MFMA16(A[rf][2], b2, acc[rf]);
    #pragma unroll
    for (int rf = 0; rf < 8; ++rf) acc[rf] = MFMA16(A[rf][3], b3, acc[rf]);
    #pragma unroll
    for (int rf = 0; rf < 8; ++rf)
        #pragma unroll
        for (int r = 0; r < 4; ++r) rmax[rf][r] = fmaxf(rmax[rf][r], acc[rf][r]);
}

// ---------- K3: SINGLE screen pass -> per-(row, 1024q-strip) max u16 ---------
// r9-proven kernel: block = 4 waves x same 1024-q strip (B shared via L1/L2),
// wave owns 128 rows (A in 128 VGPRs). Grid 512 = 8 rowblocks x 64 qsplits,
// XCD-swizzled (2 MB of qb per XCD, L2-resident). Strip max stored round-UP.
__global__ __launch_bounds__(256, 2) void k_smax(const short* __restrict__ pnb,
                                                 const short* __restrict__ qb,
                                                 unsigned short* __restrict__ sm) {
    int tid = threadIdx.x;
    int lane = tid & 63, wv = tid >> 6;
    int n16 = lane & 15, quad = lane >> 4;

    int id = blockIdx.x;                // 0..511
    int xcd = id & 7;
    int g = id >> 3;                    // 0..63
    int rowblk = g & 7;
    int qsub = g >> 3;
    int qsplit = xcd * 8 + qsub;        // 64 strips of 1024 q
    int rowbase = rowblk * 512 + wv * 128;
    int qstart = qsplit * 1024;

    short8 A[8][4];
    #pragma unroll
    for (int rf = 0; rf < 8; ++rf) {
        const short* ap = pnb + (size_t)(rowbase + rf * 16 + n16) * 128 + quad * 8;
        #pragma unroll
        for (int kk = 0; kk < 4; ++kk)
            A[rf][kk] = *(const short8*)(ap + kk * 32);
    }

    float rmax[8][4];
    #pragma unroll
    for (int rf = 0; rf < 8; ++rf)
        #pragma unroll
        for (int r = 0; r < 4; ++r) rmax[rf][r] = -1e30f;

    const short* lp = qb + (size_t)(qstart + n16) * 128 + quad * 8;
    short8 a0 = *(const short8*)(lp), a1 = *(const short8*)(lp + 32),
           a2 = *(const short8*)(lp + 64), a3 = *(const short8*)(lp + 96);

    for (int t = 0; t < 64; t += 2) {
        if ((t & 15) == 0) __syncthreads();    // keep waves converged for B sharing
        const short* p1p = lp + 2048;
        short8 b0 = *(const short8*)(p1p), b1 = *(const short8*)(p1p + 32),
               b2 = *(const short8*)(p1p + 64), b3 = *(const short8*)(p1p + 96);
        tile_max(A, a0, a1, a2, a3, rmax);
        const short* p2p = lp + 4096;          // tail over-read lands in pnb (safe)
        a0 = *(const short8*)(p2p); a1 = *(const short8*)(p2p + 32);
        a2 = *(const short8*)(p2p + 64); a3 = *(const short8*)(p2p + 96);
        tile_max(A, b0, b1, b2, b3, rmax);
        lp += 4096;
    }

    // end-of-kernel: reduce over n16 lanes, store round-up u16 strip max
    #pragma unroll
    for (int rf = 0; rf < 8; ++rf)
        #pragma unroll
        for (int r = 0; r < 4; ++r) {
            float v = rmax[rf][r];
            v = fmaxf(v, __shfl_xor(v, 1));
            v = fmaxf(v, __shfl_xor(v, 2));
            v = fmaxf(v, __shfl_xor(v, 4));
            v = fmaxf(v, __shfl_xor(v, 8));
            if (n16 == 0) {
                unsigned int s = (ordered_bits(v) >> 16) + 1u;
                if (s > 0xFFFFu) s = 0xFFFFu;
                sm[(size_t)(rowbase + rf * 16 + quad * 4 + r) * 64 + qsplit]
                    = (unsigned short)s;
            }
        }
}

// ---------- K4: per row: rowmax over 64 strip maxes -> emit flagged pairs ----
__global__ void k_pairs(const unsigned short* __restrict__ sm,
                        unsigned int* __restrict__ paircnt,
                        unsigned int* __restrict__ pairs) {
    int row = blockIdx.x;               // 0..4095
    int l = threadIdx.x;                // 0..63 = strip
    unsigned int v = sm[(size_t)row * 64 + l];
    unsigned int m = v;
    #pragma unroll
    for (int o = 32; o; o >>= 1) m = max(m, __shfl_xor(m, o));
    float vmax = from_ordered((m - 1u) << 16);   // <= true bf16 rowmax
    unsigned int thrU = ordered_bits(vmax - EPS_MARGIN) >> 16;  // trunc: conservative
    if (v >= thrU) {
        unsigned int pos = atomicAdd(paircnt, 1u);
        if (pos < PAIR_CAP) pairs[pos] = ((unsigned int)row << 6) | (unsigned int)l;
    }
}

// ---------- K5: bin pairs by strip (single block) ----------
__global__ void k_bin(const unsigned int* __restrict__ paircnt,
                      const unsigned int* __restrict__ pairs,
                      unsigned int* __restrict__ strip_off,
                      unsigned short* __restrict__ srows) {
    __shared__ unsigned int cnt[64], off[65], cur[64];
    int tid = threadIdx.x;
    unsigned int n = *paircnt; if (n > PAIR_CAP) n = PAIR_CAP;
    if (tid < 64) cnt[tid] = 0;
    __syncthreads();
    for (unsigned int i = tid; i < n; i += 256)
        atomicAdd(&cnt[pairs[i] & 63u], 1u);
    __syncthreads();
    if (tid == 0) {
        unsigned int acc = 0;
        for (int s = 0; s < 64; ++s) { off[s] = acc; acc += cnt[s]; }
        off[64] = acc;
    }
    __syncthreads();
    if (tid < 64) { cur[tid] = off[tid]; strip_off[tid] = off[tid]; }
    if (tid == 0) strip_off[64] = off[64];
    __syncthreads();
    for (unsigned int i = tid; i < n; i += 256) {
        unsigned int p = pairs[i];
        unsigned int pos = atomicAdd(&cur[p & 63u], 1u);
        srows[pos] = (unsigned short)(p >> 6);
    }
}

// ---------- K6: exact fp32 re-rank, one block per (strip, 64q-subtile) -------
// Stage 64 q x 128 fp32 in LDS once; all rows flagged on the strip reuse it.
// Thread t: q = t/4, k-quarter (t%4)*32; shfl-combine -> dot; per-wave packed
// atomicMax(best[row]) (lowest q wins ties).
__global__ __launch_bounds__(256) void k_sexact(const float* __restrict__ pn,
                                                const float* __restrict__ queue,
                                                const unsigned int* __restrict__ strip_off,
                                                const unsigned short* __restrict__ srows,
                                                unsigned long long* __restrict__ best) {
    __shared__ float qlds[64 * 132];
    int tid = threadIdx.x;
    int s = blockIdx.x >> 4, sub = blockIdx.x & 15;
    unsigned int lo = strip_off[s], hi = strip_off[s + 1];
    if (lo >= hi) return;               // uniform: whole block exits together
    int q0 = s * 1024 + sub * 64;
    const float4* qs = (const float4*)(queue + (size_t)q0 * 128);
    for (int i = tid; i < 2048; i += 256) {
        float4 v = qs[i];
        float* d = &qlds[(i >> 5) * 132 + (i & 31) * 4];
        d[0] = v.x; d[1] = v.y; d[2] = v.z; d[3] = v.w;
    }
    __syncthreads();
    int q = tid >> 2, kq = (tid & 3) * 32;
    int lane = tid & 63;
    const float* qr = &qlds[q * 132 + kq];
    for (unsigned int idx = lo; idx < hi; ++idx) {
        int row = srows[idx];
        const float4* pr = (const float4*)(pn + (size_t)row * 128 + kq);
        float acc = 0.0f;
        #pragma unroll
        for (int j = 0; j < 8; ++j) {
            float4 x = pr[j];
            acc += x.x * qr[j * 4 + 0] + x.y * qr[j * 4 + 1]
                 + x.z * qr[j * 4 + 2] + x.w * qr[j * 4 + 3];
        }
        acc += __shfl_xor(acc, 1);
        acc += __shfl_xor(acc, 2);      // all 4 lanes of the quad hold full dot
        unsigned long long pk = ((unsigned long long)ordered_bits(acc) << 32)
                              | (unsigned long long)(unsigned int)(~(unsigned int)(q0 + q));
        #pragma unroll
        for (int o = 32; o; o >>= 1) {
            unsigned long long o2 = __shfl_xor(pk, o);
            if (o2 > pk) pk = o2;
        }
        if (lane == 0) atomicMax(&best[row], pk);
    }
}

// ---------- K7: gather nn -> bf16 + EXACT fp32 diagonal ----------
__global__ void k_gather(const float* __restrict__ queue, const float* __restrict__ pn,
                         const unsigned long long* __restrict__ best,
                         short* __restrict__ nnb,
                         float* __restrict__ dg1, float* __restrict__ dg2) {
    int row = blockIdx.x;               // 0..4095
    int t = threadIdx.x;                // 0..63
    unsigned int idx = ~(unsigned int)(best[row] & 0xFFFFFFFFull);
    idx &= 0xFFFFu;
    float2 v = ((const float2*)(queue + (size_t)idx * 128))[t];
    unsigned int pk = (unsigned int)(unsigned short)bf_rne(v.x)
                    | ((unsigned int)(unsigned short)bf_rne(v.y) << 16);
    ((unsigned int*)(nnb + (size_t)row * 128))[t] = pk;
    const float* partner = (row < 2048) ? pn + (size_t)(2048 + row) * 128
                                        : pn + (size_t)(row - 2048) * 128;
    float2 p = ((const float2*)partner)[t];
    float d = v.x * p.x + v.y * p.y;
    #pragma unroll
    for (int o = 32; o; o >>= 1) d += __shfl_xor(d, o);
    if (t == 0) {
        if (row < 2048) dg1[row] = d;
        else dg2[row - 2048] = d;
    }
}

// ---------- K8: MFMA gemm+LSE partials: A(bf16) x B(bf16)^T -> exp sums ------
__global__ __launch_bounds__(256) void k_glse(const short* __restrict__ Ab,
                                              const short* __restrict__ Bb,
                                              float* __restrict__ rowsum,
                                              float* __restrict__ colsum) {
    int tid = threadIdx.x;
    int lane = tid & 63, wv = tid >> 6;
    int n16 = lane & 15, quad = lane >> 4;
    int rowbase = blockIdx.x * 64, colbase = blockIdx.y * 64;

    short8 A[4][4], B[4];
    #pragma unroll
    for (int rf = 0; rf < 4; ++rf) {
        const short* ap = Ab + (size_t)(rowbase + rf * 16 + n16) * 128 + quad * 8;
        #pragma unroll
        for (int kk = 0; kk < 4; ++kk) A[rf][kk] = *(const short8*)(ap + kk * 32);
    }
    const short* bp = Bb + (size_t)(colbase + wv * 16 + n16) * 128 + quad * 8;
    #pragma unroll
    for (int kk = 0; kk < 4; ++kk) B[kk] = *(const short8*)(bp + kk * 32);

    floatx4 acc[4];
    floatx4 zero = {0.0f, 0.0f, 0.0f, 0.0f};
    #pragma unroll
    for (int rf = 0; rf < 4; ++rf) acc[rf] = MFMA16(A[rf][0], B[0], zero);
    #pragma unroll
    for (int rf = 0; rf < 4; ++rf) acc[rf] = MFMA16(A[rf][1], B[1], acc[rf]);
    #pragma unroll
    for (int rf = 0; rf < 4; ++rf) acc[rf] = MFMA16(A[rf][2], B[2], acc[rf]);
    #pragma unroll
    for (int rf = 0; rf < 4; ++rf) acc[rf] = MFMA16(A[rf][3], B[3], acc[rf]);

    float e[4][4], csum = 0.0f;
    #pragma unroll
    for (int rf = 0; rf < 4; ++rf)
        #pragma unroll
        for (int r = 0; r < 4; ++r) {
            e[rf][r] = __expf(acc[rf][r] * SCALE - 10.0f);
            csum += e[rf][r];
        }
    #pragma unroll
    for (int rf = 0; rf < 4; ++rf)
        #pragma unroll
        for (int r = 0; r < 4; ++r) {
            float v = e[rf][r];
            v += __shfl_xor(v, 1);
            v += __shfl_xor(v, 2);
            v += __shfl_xor(v, 4);
            v += __shfl_xor(v, 8);
            if (n16 == 0)
                atomicAdd(&rowsum[rowbase + rf * 16 + quad * 4 + r], v);
        }
    csum += __shfl_xor(csum, 16);
    csum += __shfl_xor(csum, 32);
    if (quad == 0)
        atomicAdd(&colsum[colbase + wv * 16 + n16], csum);
}

// ---------- K9: final loss ----------
__global__ void k_final(const float* __restrict__ sums,
                        const float* __restrict__ dg1, const float* __restrict__ dg2,
                        float* __restrict__ out) {
    int idx = blockIdx.x * 256 + threadIdx.x;    // 0..8191
    int seg = idx >> 11, r = idx & 2047;
    float s = sums[seg * 2048 + r];
    float d = (seg < 2) ? dg1[r] : dg2[r];
    out[idx] = 10.0f + logf(s) - d * SCALE;
}

extern "C" void kernel_launch(void* const* d_in, const int* in_sizes, int n_in,
                              void* d_out, int out_size, void* d_ws, size_t ws_size,
                              hipStream_t stream) {
    const float* p1    = (const float*)d_in[0];   // [2048,128]
    const float* p2    = (const float*)d_in[1];   // [2048,128]
    const float* queue = (const float*)d_in[2];   // [65536,128]
    float* out = (float*)d_out;                   // [8192]

    char* w = (char*)d_ws;                        // footprint ~21 MiB
    float* pn  = (float*)w;                               // 2 MB  fp32 [4096,128]
    short* nnb = (short*)(w + (2u << 20));                // 1 MB  bf16 [4096,128]
    short* qb  = (short*)(w + (3u << 20));                // 16 MB bf16 [65536,128]
    short* pnb = (short*)(w + (19u << 20));               // 1 MB  bf16 [4096,128]
    char* b2 = w + (20u << 20);
    unsigned short* sm = (unsigned short*)b2;                       // 512 KB [4096,64]
    unsigned long long* best = (unsigned long long*)(b2 + (512u << 10)); // 32 KB
    unsigned int* paircnt = (unsigned int*)(b2 + (544u << 10));     // 256 B
    unsigned int* pairs = (unsigned int*)(b2 + (545u << 10));       // 128 KB
    unsigned int* strip_off = (unsigned int*)(b2 + (673u << 10));   // 1 KB (65 u32)
    unsigned short* srows = (unsigned short*)(b2 + (674u << 10));   // 64 KB
    float* sums = (float*)(b2 + (802u << 10));                      // 32 KB
    float* dg1  = sums + 8192;                                      // 8 KB
    float* dg2  = dg1 + 2048;                                       // 8 KB

    k_prep<<<4096, 64, 0, stream>>>(p1, p2, pn, pnb, best, paircnt, sums);
    k_qcvt<<<4096, 256, 0, stream>>>(queue, qb);
    k_smax<<<512, 256, 0, stream>>>(pnb, qb, sm);
    k_pairs<<<4096, 64, 0, stream>>>(sm, paircnt, pairs);
    k_bin<<<1, 256, 0, stream>>>(paircnt, pairs, strip_off, srows);
    k_sexact<<<1024, 256, 0, stream>>>(pn, queue, strip_off, srows, best);
    k_gather<<<4096, 64, 0, stream>>>(queue, pn, best, nnb, dg1, dg2);

    // M1 = nn1 @ p2n^T : rows -> loss[0..2047], cols -> loss[2048..4095]
    k_glse<<<dim3(32, 32), 256, 0, stream>>>(nnb, pnb + 2048 * 128,
                                             sums, sums + 2048);
    // M2 = nn2 @ p1n^T : rows -> loss[4096..6143], cols -> loss[6144..8191]
    k_glse<<<dim3(32, 32), 256, 0, stream>>>(nnb + 2048 * 128, pnb,
                                             sums + 4096, sums + 6144);
    k_final<<<32, 256, 0, stream>>>(sums, dg1, dg2, out);
}